// Round 13
// baseline (226.311 us; speedup 1.0000x reference)
//
#include <hip/hip_runtime.h>
#include <hip/hip_bf16.h>

#define NT 16384   // tokens
#define DM 4096    // d_model
#define NE 64      // experts
#define MB 16      // tokens per block
#define BK 128     // K per LDS stage
#define NST (DM / BK)   // 32 stages, 4 ksteps each
#define LST 129    // padded LDS row stride in floats (conflict-free A-frag reads)

typedef __attribute__((ext_vector_type(8))) short bf16x8;   // 8 bf16 = 4 VGPRs
typedef __attribute__((ext_vector_type(4))) float f32x4;

__device__ __forceinline__ unsigned short bf16_rne(float f) {
  const unsigned u = __float_as_uint(f);
  return (unsigned short)((u + 0x7FFFu + ((u >> 16) & 1u)) >> 16);
}

// hi/lo split of a float pair via packed HW cvt (validated R7-R11 class)
__device__ __forceinline__ void split2(float fa, float fb, unsigned& hp, unsigned& lp) {
  union { __hip_bfloat162 h; unsigned u; } cv;
  cv.h = __float22bfloat162_rn(make_float2(fa, fb));
  hp = cv.u;
  const float ha = __uint_as_float(hp << 16);
  const float hb = __uint_as_float(hp & 0xFFFF0000u);
  cv.h = __float22bfloat162_rn(make_float2(fa - ha, fb - hb));
  lp = cv.u;
}

__device__ __forceinline__ void splitA(const float4& c0, const float4& c1,
                                       bf16x8& hi, bf16x8& lo) {
  union { unsigned u[4]; bf16x8 v; } H, L;
  split2(c0.x, c0.y, H.u[0], L.u[0]);
  split2(c0.z, c0.w, H.u[1], L.u[1]);
  split2(c1.x, c1.y, H.u[2], L.u[2]);
  split2(c1.z, c1.w, H.u[3], L.u[3]);
  hi = H.v; lo = L.v;
}

// W pre-pass (validated, unchanged): fp32 -> split bf16 hi/lo in exact MFMA
// B-fragment order. id = ks*256 + nt*64 + lane;
// elem j = W[e=nt*16+(lane&15)][k=ks*32+(lane>>4)*8+j]. Idempotent.
__global__ void w_convert(const float* __restrict__ W,
                          unsigned short* __restrict__ Whi,
                          unsigned short* __restrict__ Wlo) {
  const int id   = blockIdx.x * 256 + threadIdx.x;  // 0..32767
  const int lane = id & 63;
  const int nt   = (id >> 6) & 3;
  const int ks   = id >> 8;                         // 0..127
  const float* src = W + (size_t)(nt * 16 + (lane & 15)) * DM + ks * 32 + (lane >> 4) * 8;
  unsigned short h[8], l[8];
#pragma unroll
  for (int j = 0; j < 8; ++j) {
    const float f = src[j];
    h[j] = bf16_rne(f);
    l[j] = bf16_rne(f - __uint_as_float((unsigned)h[j] << 16));
  }
  uint4 ph, pl;
  ph.x = h[0] | ((unsigned)h[1] << 16); ph.y = h[2] | ((unsigned)h[3] << 16);
  ph.z = h[4] | ((unsigned)h[5] << 16); ph.w = h[6] | ((unsigned)h[7] << 16);
  pl.x = l[0] | ((unsigned)l[1] << 16); pl.y = l[2] | ((unsigned)l[3] << 16);
  pl.z = l[4] | ((unsigned)l[5] << 16); pl.w = l[6] | ((unsigned)l[7] << 16);
  *(uint4*)(Whi + (size_t)id * 8) = ph;
  *(uint4*)(Wlo + (size_t)id * 8) = pl;
}

// ---- staging / compute macros (statically named sets; rule #20).
// NOTE: macro params named so ## pastes only with literal a/b suffixes.
#define LDG_(gs, st) {                                           \
    const float* _p = xgs + (size_t)(st) * BK;                   \
    gs##a = *(const float4*)(_p);                                \
    gs##b = *(const float4*)(_p + 4); }

#define WST_(bi, gs) {                                           \
    float* _q = &xs[bi][srow][scol];                             \
    *(float4*)(_q)     = gs##a;                                  \
    *(float4*)(_q + 4) = gs##b; }

#define KSTEP_(bi, kk, BH, BL) {                                                   \
    const float* _ar = &xs[bi][lane & 15][(kk) * 32 + (lane >> 4) * 8];            \
    const float4 _f0 = *(const float4*)(_ar);                                      \
    const float4 _f1 = *(const float4*)(_ar + 4);                                  \
    bf16x8 _ah, _al;                                                               \
    splitA(_f0, _f1, _ah, _al);                                                    \
    acc = __builtin_amdgcn_mfma_f32_16x16x32_bf16(_al, BL, acc, 0, 0, 0);          \
    acc = __builtin_amdgcn_mfma_f32_16x16x32_bf16(_al, BH, acc, 0, 0, 0);          \
    acc = __builtin_amdgcn_mfma_f32_16x16x32_bf16(_ah, BL, acc, 0, 0, 0);          \
    acc = __builtin_amdgcn_mfma_f32_16x16x32_bf16(_ah, BH, acc, 0, 0, 0); }

// Main: block = 256 thr = 4 waves = 16 tokens x 64 experts (wave wv -> experts
// [16wv,16wv+16), full K). x staged row-coalesced global->reg->LDS (2 stages
// ahead; T14 async-split), LDS rows padded to 129 floats -> conflict-free
// ds_read_b128 A-frags. B frags (precomputed order, L2-hot) loaded per stage.
// Tiny footprint (~90 VGPR, 22 KiB LDS) -> 4 blocks/CU: cross-block TLP hides
// all stalls/barriers. 4-pass split-bf16 mfma (validated numerics R7-R11).
__launch_bounds__(256, 4)
__global__ void moe_mfma(const float* __restrict__ x,
                         const unsigned short* __restrict__ Whi,
                         const unsigned short* __restrict__ Wlo,
                         float* __restrict__ out,
                         float* __restrict__ bsum) {
  __shared__ float xs[2][MB][LST];   // 16.1 KiB (two 8 KiB stages, padded)
  __shared__ float lg[MB][NE + 2];   // 4.1 KiB
  __shared__ float esums[4][NE];     // 1 KiB

  const int tid  = threadIdx.x;
  const int lane = tid & 63;
  const int wvu  = __builtin_amdgcn_readfirstlane(tid >> 6);  // expert group 0..3
  const int blk  = blockIdx.x;
  const int tok0 = blk * MB;

  // staging role: thread t -> row t>>4 (0..15), float cols (t&15)*8 .. +7
  const int srow = tid >> 4;
  const int scol = (tid & 15) * 8;
  const float* xgs = x + (size_t)(tok0 + srow) * DM + scol;

  // B frag base (shorts): ks*2048 + nt*512 + lane*8, nt = wvu
  const unsigned short* bhp = Whi + (size_t)wvu * 512 + lane * 8;
  const unsigned short* blp = Wlo + (size_t)wvu * 512 + lane * 8;

  f32x4 acc = (f32x4){0.f, 0.f, 0.f, 0.f};

  float4 G0a, G0b, G1a, G1b, S0a, S0b;

  // prologue: stage 0 -> buf0; pipeline G0<-1, G1<-2
  LDG_(S0, 0);
  WST_(0, S0);
  LDG_(G0, 1);
  LDG_(G1, 2);
  __syncthreads();

  for (int s = 0; s < NST; ++s) {
    const int b = s & 1;
    // B frags for this stage's 4 ksteps (issued up front; L2/L1-hot)
    {
      const size_t o = (size_t)(s * 4) * 2048;
      const bf16x8 BH0 = *(const bf16x8*)(bhp + o);
      const bf16x8 BH1 = *(const bf16x8*)(bhp + o + 2048);
      const bf16x8 BH2 = *(const bf16x8*)(bhp + o + 4096);
      const bf16x8 BH3 = *(const bf16x8*)(bhp + o + 6144);
      const bf16x8 BL0 = *(const bf16x8*)(blp + o);
      const bf16x8 BL1 = *(const bf16x8*)(blp + o + 2048);
      const bf16x8 BL2 = *(const bf16x8*)(blp + o + 4096);
      const bf16x8 BL3 = *(const bf16x8*)(blp + o + 6144);
      KSTEP_(b, 0, BH0, BL0);
      KSTEP_(b, 1, BH1, BL1);
      KSTEP_(b, 2, BH2, BL2);
      KSTEP_(b, 3, BH3, BL3);
    }
    // write next stage into the other buffer (loads issued 2 stages ago ->
    // ~900cy latency already absorbed), then refill that register set.
    if (s + 1 < NST) {
      if (b == 0) { WST_(1, G0); } else { WST_(0, G1); }
      if (s + 3 < NST) {
        if (b == 0) { LDG_(G0, s + 3); } else { LDG_(G1, s + 3); }
      }
    }
    __syncthreads();
  }

  // D layout (m89, validated): token = (lane>>4)*4 + r, expert = 16*wvu + (lane&15)
#pragma unroll
  for (int r = 0; r < 4; ++r)
    lg[(lane >> 4) * 4 + r][wvu * 16 + (lane & 15)] = acc[r];
  __syncthreads();

  // Epilogue (validated verbatim): wave wvu owns tokens tok0 + 4wvu + {0..3}.
  float esum = 0.f;
#pragma unroll
  for (int ti = 0; ti < 4; ++ti) {
    const int t = 4 * wvu + ti;
    const float lgv = lg[t][lane];

    float m = lgv;
#pragma unroll
    for (int off = 32; off; off >>= 1) m = fmaxf(m, __shfl_xor(m, off, 64));
    const float p = __expf(lgv - m);
    float Z = p;
#pragma unroll
    for (int off = 32; off; off >>= 1) Z += __shfl_xor(Z, off, 64);
    const float s = p / Z;
    esum += s;

    // top-1 (value desc, index asc — matches lax.top_k tie-break)
    float v1 = s; int i1 = lane;
#pragma unroll
    for (int off = 32; off; off >>= 1) {
      const float ov = __shfl_xor(v1, off, 64);
      const int   oi = __shfl_xor(i1, off, 64);
      if (ov > v1 || (ov == v1 && oi < i1)) { v1 = ov; i1 = oi; }
    }
    // top-2: mask winner (scores >= 0, so -1 acts as -inf)
    float sv = (lane == i1) ? -1.f : s;
    float v2 = sv; int i2 = lane;
#pragma unroll
    for (int off = 32; off; off >>= 1) {
      const float ov = __shfl_xor(v2, off, 64);
      const int   oi = __shfl_xor(i2, off, 64);
      if (ov > v2 || (ov == v2 && oi < i2)) { v2 = ov; i2 = oi; }
    }

    if (lane == 0) {
      const int gt = tok0 + t;
      const float inv = 1.f / (v1 + v2);
      out[2 * gt]              = v1 * inv;
      out[2 * gt + 1]          = v2 * inv;
      out[2 * NT + 2 * gt]     = (float)i1;
      out[2 * NT + 2 * gt + 1] = (float)i2;
    }
  }

  // per-block expert score sums (deterministic tree reduce, no atomics)
  esums[wvu][lane] = esum;
  __syncthreads();
  if (wvu == 0) {
    float tot = esums[0][lane] + esums[1][lane] + esums[2][lane] + esums[3][lane];
    bsum[blk * NE + lane] = tot;
  }
}

// Reduce NT/MB per-block expert sums -> load balancing loss
__global__ void moe_gate_loss(const float* __restrict__ bsum,
                              float* __restrict__ out) {
  __shared__ float red[4][64];
  const int e = threadIdx.x & 63;
  const int g = threadIdx.x >> 6;
  float s = 0.f;
  for (int b = g; b < NT / MB; b += 4) s += bsum[b * 64 + e];
  red[g][e] = s;
  __syncthreads();
  if (threadIdx.x < 64) {
    const float tot = red[0][e] + red[1][e] + red[2][e] + red[3][e];
    const float p = tot * (1.f / (float)NT);
    float term = p * logf(p + 1e-8f);
#pragma unroll
    for (int off = 32; off; off >>= 1) term += __shfl_xor(term, off, 64);
    if (e == 0) out[4 * NT] = term;  // out[65536]
  }
}

extern "C" void kernel_launch(void* const* d_in, const int* in_sizes, int n_in,
                              void* d_out, int out_size, void* d_ws, size_t ws_size,
                              hipStream_t stream) {
  const float* x = (const float*)d_in[0];   // [16384, 4096]
  const float* W = (const float*)d_in[1];   // [64, 4096]
  float* out = (float*)d_out;               // scores[32768] | idx[32768] | loss[1]

  unsigned short* Whi = (unsigned short*)d_ws;        // 512 KiB
  unsigned short* Wlo = Whi + (size_t)NE * DM;        // 512 KiB
  float* bsum = (float*)(Wlo + (size_t)NE * DM);      // [1024][64] = 256 KiB

  hipLaunchKernelGGL(w_convert, dim3(128), dim3(256), 0, stream, W, Whi, Wlo);
  hipLaunchKernelGGL(moe_mfma, dim3(NT / MB), dim3(256), 0, stream, x, Whi, Wlo, out, bsum);
  hipLaunchKernelGGL(moe_gate_loss, dim3(1), dim3(256), 0, stream, bsum, out);
}

// Round 14
// 150.933 us; speedup vs baseline: 1.4994x; 1.4994x over previous
//
#include <hip/hip_runtime.h>
#include <hip/hip_bf16.h>

#define NT 16384   // tokens
#define DM 4096    // d_model
#define NE 64      // experts
#define MB 16      // tokens per block
#define BK 128     // K per glds stage (4 ksteps)
#define NST (DM / BK)   // 32 stages

typedef __attribute__((ext_vector_type(8))) short bf16x8;   // 8 bf16 = 4 VGPRs
typedef __attribute__((ext_vector_type(4))) float f32x4;
typedef __attribute__((address_space(3))) float lds_f;
typedef __attribute__((address_space(1))) const float glb_f;

__device__ __forceinline__ unsigned short bf16_rne(float f) {
  const unsigned u = __float_as_uint(f);
  return (unsigned short)((u + 0x7FFFu + ((u >> 16) & 1u)) >> 16);
}

// hi/lo split of a float pair via packed HW cvt (validated R7-R13 class)
__device__ __forceinline__ void split2(float fa, float fb, unsigned& hp, unsigned& lp) {
  union { __hip_bfloat162 h; unsigned u; } cv;
  cv.h = __float22bfloat162_rn(make_float2(fa, fb));
  hp = cv.u;
  const float ha = __uint_as_float(hp << 16);
  const float hb = __uint_as_float(hp & 0xFFFF0000u);
  cv.h = __float22bfloat162_rn(make_float2(fa - ha, fb - hb));
  lp = cv.u;
}

__device__ __forceinline__ void splitA(const float4& c0, const float4& c1,
                                       bf16x8& hi, bf16x8& lo) {
  union { unsigned u[4]; bf16x8 v; } H, L;
  split2(c0.x, c0.y, H.u[0], L.u[0]);
  split2(c0.z, c0.w, H.u[1], L.u[1]);
  split2(c1.x, c1.y, H.u[2], L.u[2]);
  split2(c1.z, c1.w, H.u[3], L.u[3]);
  hi = H.v; lo = L.v;
}

// W pre-pass (validated, unchanged): fp32 -> split bf16 hi/lo in exact MFMA
// B-fragment order. id = ks*256 + nt*64 + lane;
// elem j = W[e=nt*16+(lane&15)][k=ks*32+(lane>>4)*8+j]. Idempotent.
__global__ void w_convert(const float* __restrict__ W,
                          unsigned short* __restrict__ Whi,
                          unsigned short* __restrict__ Wlo) {
  const int id   = blockIdx.x * 256 + threadIdx.x;  // 0..32767
  const int lane = id & 63;
  const int nt   = (id >> 6) & 3;
  const int ks   = id >> 8;                         // 0..127
  const float* src = W + (size_t)(nt * 16 + (lane & 15)) * DM + ks * 32 + (lane >> 4) * 8;
  unsigned short h[8], l[8];
#pragma unroll
  for (int j = 0; j < 8; ++j) {
    const float f = src[j];
    h[j] = bf16_rne(f);
    l[j] = bf16_rne(f - __uint_as_float((unsigned)h[j] << 16));
  }
  uint4 ph, pl;
  ph.x = h[0] | ((unsigned)h[1] << 16); ph.y = h[2] | ((unsigned)h[3] << 16);
  ph.z = h[4] | ((unsigned)h[5] << 16); ph.w = h[6] | ((unsigned)h[7] << 16);
  pl.x = l[0] | ((unsigned)l[1] << 16); pl.y = l[2] | ((unsigned)l[3] << 16);
  pl.z = l[4] | ((unsigned)l[5] << 16); pl.w = l[6] | ((unsigned)l[7] << 16);
  *(uint4*)(Whi + (size_t)id * 8) = ph;
  *(uint4*)(Wlo + (size_t)id * 8) = pl;
}

// issue async glds for stage st into buffer bi (wave stages rows 4wvu..4wvu+4)
#define STAGE(bi, st) {                                                          \
    __builtin_amdgcn_global_load_lds((const glb_f*)(src0 + (size_t)(st) * BK),   \
        (lds_f*)(&xs[bi][4 * wvu][0]), 16, 0, 0);                                \
    __builtin_amdgcn_global_load_lds((const glb_f*)(src1 + (size_t)(st) * BK),   \
        (lds_f*)(&xs[bi][4 * wvu + 2][0]), 16, 0, 0); }

// one 16x16x32 kstep: swizzled A-frag read from LDS + 4-pass split-bf16 mfma
#define KSTEP_(bi, kk, BH, BL) {                                                   \
    const char* _b = (const char*)&xs[bi][0][0];                                   \
    const unsigned _o = aoff0 + (kk) * 128;                                        \
    const float4 _f0 = *(const float4*)(_b + _o);                                  \
    const float4 _f1 = *(const float4*)(_b + (_o ^ 16u));                          \
    bf16x8 _ah, _al;                                                               \
    splitA(_f0, _f1, _ah, _al);                                                    \
    acc = __builtin_amdgcn_mfma_f32_16x16x32_bf16(_al, BL, acc, 0, 0, 0);          \
    acc = __builtin_amdgcn_mfma_f32_16x16x32_bf16(_al, BH, acc, 0, 0, 0);          \
    acc = __builtin_amdgcn_mfma_f32_16x16x32_bf16(_ah, BL, acc, 0, 0, 0);          \
    acc = __builtin_amdgcn_mfma_f32_16x16x32_bf16(_ah, BH, acc, 0, 0, 0); }

// Main: block = 256 thr = 4 waves = 16 tokens x 64 experts (wave wv -> experts
// [16wv,16wv+16), full K). x staged via global_load_lds at STAGE TOP (m97
// pattern: async load overlaps this stage's compute; barrier drain absorbs
// only the residual). LDS linear dest + pre-swizzled global source
// (col ^= (row&7)<<4); reads apply the same XOR -> optimal b128 bank spread.
// Tiny footprint (~90 VGPR, 21.6 KiB LDS) -> 4 blocks/CU co-resident (grid
// 1024): cross-block TLP covers drains. 4-pass split-bf16 mfma (validated).
__launch_bounds__(256, 4)
__global__ void moe_mfma(const float* __restrict__ x,
                         const unsigned short* __restrict__ Whi,
                         const unsigned short* __restrict__ Wlo,
                         float* __restrict__ out,
                         float* __restrict__ bsum) {
  __shared__ float xs[2][MB][BK];    // 16 KiB linear (glds dest), swizzled content
  __shared__ float lg[MB][NE + 2];   // 4.1 KiB
  __shared__ float esums[4][NE];     // 1 KiB

  const int tid  = threadIdx.x;
  const int lane = tid & 63;
  const int wvu  = __builtin_amdgcn_readfirstlane(tid >> 6);  // expert group 0..3
  const int blk  = blockIdx.x;
  const int tok0 = blk * MB;

  // staging source: call 0 -> rows 4wvu + (lane>>5); call 1 -> +2.
  // source col pre-swizzled so linear LDS holds content[B] = x[row][B ^ ((row&7)<<4)].
  const int r0  = 4 * wvu + (lane >> 5);
  const int r1  = r0 + 2;
  const int sw0 = ((((lane & 31) * 16) ^ ((r0 & 7) << 4)) >> 2);  // float offset
  const int sw1 = ((((lane & 31) * 16) ^ ((r1 & 7) << 4)) >> 2);
  const float* src0 = x + (size_t)(tok0 + r0) * DM + sw0;
  const float* src1 = x + (size_t)(tok0 + r1) * DM + sw1;

  // B frag base (shorts): ks*2048 + nt*512 + lane*8, nt = wvu
  const unsigned short* bhp = Whi + (size_t)wvu * 512 + lane * 8;
  const unsigned short* blp = Wlo + (size_t)wvu * 512 + lane * 8;

  // A-frag read base (bytes): row=(lane&15), chunk=(lane>>4)*32 ^ swizzle
  const unsigned aoff0 =
      (unsigned)((lane & 15) * 512 + (((lane >> 4) * 32) ^ ((lane & 7) << 4)));

  f32x4 acc = (f32x4){0.f, 0.f, 0.f, 0.f};

  // prologue: stage 0 -> buf 0 (drained by the barrier)
  STAGE(0, 0);
  __syncthreads();

  for (int s = 0; s < NST; ++s) {
    const int b = s & 1;
    // 1. issue next stage FIRST (async; overlaps all compute below)
    if (s + 1 < NST) STAGE(b ^ 1, s + 1);
    // 2. B frags for this stage's 4 ksteps (L2-hot, lane-contiguous)
    const size_t o = (size_t)(s * 4) * 2048;
    const bf16x8 BH0 = *(const bf16x8*)(bhp + o);
    const bf16x8 BH1 = *(const bf16x8*)(bhp + o + 2048);
    const bf16x8 BH2 = *(const bf16x8*)(bhp + o + 4096);
    const bf16x8 BH3 = *(const bf16x8*)(bhp + o + 6144);
    const bf16x8 BL0 = *(const bf16x8*)(blp + o);
    const bf16x8 BL1 = *(const bf16x8*)(blp + o + 2048);
    const bf16x8 BL2 = *(const bf16x8*)(blp + o + 4096);
    const bf16x8 BL3 = *(const bf16x8*)(blp + o + 6144);
    // 3. compute current buffer
    KSTEP_(b, 0, BH0, BL0);
    KSTEP_(b, 1, BH1, BL1);
    KSTEP_(b, 2, BH2, BL2);
    KSTEP_(b, 3, BH3, BL3);
    // 4. barrier (drains the stage issued at step 1 -> next buf ready)
    __syncthreads();
  }

  // D layout (m89, validated): token = (lane>>4)*4 + r, expert = 16*wvu + (lane&15)
#pragma unroll
  for (int r = 0; r < 4; ++r)
    lg[(lane >> 4) * 4 + r][wvu * 16 + (lane & 15)] = acc[r];
  __syncthreads();

  // Epilogue (validated verbatim): wave wvu owns tokens tok0 + 4wvu + {0..3}.
  float esum = 0.f;
#pragma unroll
  for (int ti = 0; ti < 4; ++ti) {
    const int t = 4 * wvu + ti;
    const float lgv = lg[t][lane];

    float m = lgv;
#pragma unroll
    for (int off = 32; off; off >>= 1) m = fmaxf(m, __shfl_xor(m, off, 64));
    const float p = __expf(lgv - m);
    float Z = p;
#pragma unroll
    for (int off = 32; off; off >>= 1) Z += __shfl_xor(Z, off, 64);
    const float s = p / Z;
    esum += s;

    // top-1 (value desc, index asc — matches lax.top_k tie-break)
    float v1 = s; int i1 = lane;
#pragma unroll
    for (int off = 32; off; off >>= 1) {
      const float ov = __shfl_xor(v1, off, 64);
      const int   oi = __shfl_xor(i1, off, 64);
      if (ov > v1 || (ov == v1 && oi < i1)) { v1 = ov; i1 = oi; }
    }
    // top-2: mask winner (scores >= 0, so -1 acts as -inf)
    float sv = (lane == i1) ? -1.f : s;
    float v2 = sv; int i2 = lane;
#pragma unroll
    for (int off = 32; off; off >>= 1) {
      const float ov = __shfl_xor(v2, off, 64);
      const int   oi = __shfl_xor(i2, off, 64);
      if (ov > v2 || (ov == v2 && oi < i2)) { v2 = ov; i2 = oi; }
    }

    if (lane == 0) {
      const int gt = tok0 + t;
      const float inv = 1.f / (v1 + v2);
      out[2 * gt]              = v1 * inv;
      out[2 * gt + 1]          = v2 * inv;
      out[2 * NT + 2 * gt]     = (float)i1;
      out[2 * NT + 2 * gt + 1] = (float)i2;
    }
  }

  // per-block expert score sums (deterministic tree reduce, no atomics)
  esums[wvu][lane] = esum;
  __syncthreads();
  if (wvu == 0) {
    float tot = esums[0][lane] + esums[1][lane] + esums[2][lane] + esums[3][lane];
    bsum[blk * NE + lane] = tot;
  }
}

// Reduce NT/MB per-block expert sums -> load balancing loss
__global__ void moe_gate_loss(const float* __restrict__ bsum,
                              float* __restrict__ out) {
  __shared__ float red[4][64];
  const int e = threadIdx.x & 63;
  const int g = threadIdx.x >> 6;
  float s = 0.f;
  for (int b = g; b < NT / MB; b += 4) s += bsum[b * 64 + e];
  red[g][e] = s;
  __syncthreads();
  if (threadIdx.x < 64) {
    const float tot = red[0][e] + red[1][e] + red[2][e] + red[3][e];
    const float p = tot * (1.f / (float)NT);
    float term = p * logf(p + 1e-8f);
#pragma unroll
    for (int off = 32; off; off >>= 1) term += __shfl_xor(term, off, 64);
    if (e == 0) out[4 * NT] = term;  // out[65536]
  }
}

extern "C" void kernel_launch(void* const* d_in, const int* in_sizes, int n_in,
                              void* d_out, int out_size, void* d_ws, size_t ws_size,
                              hipStream_t stream) {
  const float* x = (const float*)d_in[0];   // [16384, 4096]
  const float* W = (const float*)d_in[1];   // [64, 4096]
  float* out = (float*)d_out;               // scores[32768] | idx[32768] | loss[1]

  unsigned short* Whi = (unsigned short*)d_ws;        // 512 KiB
  unsigned short* Wlo = Whi + (size_t)NE * DM;        // 512 KiB
  float* bsum = (float*)(Wlo + (size_t)NE * DM);      // [1024][64] = 256 KiB

  hipLaunchKernelGGL(w_convert, dim3(128), dim3(256), 0, stream, W, Whi, Wlo);
  hipLaunchKernelGGL(moe_mfma, dim3(NT / MB), dim3(256), 0, stream, x, Whi, Wlo, out, bsum);
  hipLaunchKernelGGL(moe_gate_loss, dim3(1), dim3(256), 0, stream, bsum, out);
}